// Round 3
// baseline (611.629 us; speedup 1.0000x reference)
//
#include <hip/hip_runtime.h>
#include <hip/hip_cooperative_groups.h>
#include <math.h>

namespace cg = cooperative_groups;

#define Bq 8
#define Sq 2048
#define Hq 2048
#define BSq (Bq*Sq)
#define GRIDN (BSq/16)          // 1024 blocks, used for all three phases
#define K3_ROWS 16              // output rows per block in phase 3 (Bq*Sq/K3_ROWS == GRIDN)

// ---- output layout (flat float32, reference return order) ----
#define OFF_MH  ((size_t)0)                      // merged_hidden  [B,S,H]
#define OFF_MAM ((size_t)BSq*Hq)                 // merged_attention_mask [B,S]
#define OFF_MSP (OFF_MAM + (size_t)BSq)          // merged_special [B,S]
#define OFF_CNT (OFF_MSP + (size_t)BSq)          // counts [B,S]
#define OFF_MM  (OFF_CNT + (size_t)BSq)          // mm [B,S,2]
#define OFF_LG  (OFF_MM + (size_t)2*BSq)         // logits [B,S,2]

// ---- workspace layout (bytes) ----
#define WS_DOTS 0                                // float4[BSq] : d0,d1,e0,e1 per token
#define WS_V    ((size_t)BSq*16)                 // float[BSq]  : v weights
#define WS_SEG  (WS_V + (size_t)BSq*4)           // int[BSq]    : segment starts
#define WS_META (WS_SEG + (size_t)BSq*4)         // int[2*Bq]   : new_len, T per batch

// clang-native 4-float vector (accepted by __builtin_nontemporal_store)
typedef float nfloat4 __attribute__((ext_vector_type(4)));

__device__ inline float4 f4add(float4 a, float4 b) {
  return make_float4(a.x+b.x, a.y+b.y, a.z+b.z, a.w+b.w);
}

__device__ inline void nt_store_f4(float4 v, float4* p) {
  nfloat4 nv;
  nv.x = v.x; nv.y = v.y; nv.z = v.z; nv.w = v.w;
  __builtin_nontemporal_store(nv, (nfloat4*)p);
}

// ======================= phase bodies (shared by fused + fallback) ==========

// Phase 1: per-token dots. 16 tokens per block `blk`, 256 threads.
__device__ inline void phase1_dots(int blk, int tid,
                                   const float* __restrict__ hid,
                                   const float* __restrict__ Wg,
                                   float4* __restrict__ dots,
                                   float4 (*part)[256]) {
  const float4* W4 = (const float4*)Wg;
  // W row-major (4096,2): w_j(h) = W[2h+j]; e-half at float offset 4096 (float4 idx 1024)
  const float4 wa0 = W4[2*tid],           wa1 = W4[2*tid+1];
  const float4 wa2 = W4[2*(256+tid)],     wa3 = W4[2*(256+tid)+1];
  const float4 wb0 = W4[1024+2*tid],      wb1 = W4[1024+2*tid+1];
  const float4 wb2 = W4[1024+2*(256+tid)],wb3 = W4[1024+2*(256+tid)+1];
  const int base = blk * 16;
  for (int tk0 = 0; tk0 < 16; tk0 += 4) {
    #pragma unroll
    for (int j = 0; j < 4; ++j) {
      const float4* hr = (const float4*)(hid + (size_t)(base + tk0 + j) * Hq);
      float4 h0 = hr[tid], h1 = hr[256+tid];
      float d0 = h0.x*wa0.x + h0.y*wa0.z + h0.z*wa1.x + h0.w*wa1.z
               + h1.x*wa2.x + h1.y*wa2.z + h1.z*wa3.x + h1.w*wa3.z;
      float d1 = h0.x*wa0.y + h0.y*wa0.w + h0.z*wa1.y + h0.w*wa1.w
               + h1.x*wa2.y + h1.y*wa2.w + h1.z*wa3.y + h1.w*wa3.w;
      float e0 = h0.x*wb0.x + h0.y*wb0.z + h0.z*wb1.x + h0.w*wb1.z
               + h1.x*wb2.x + h1.y*wb2.z + h1.z*wb3.x + h1.w*wb3.z;
      float e1 = h0.x*wb0.y + h0.y*wb0.w + h0.z*wb1.y + h0.w*wb1.w
               + h1.x*wb2.y + h1.y*wb2.w + h1.z*wb3.y + h1.w*wb3.w;
      part[j][tid] = make_float4(d0, d1, e0, e1);
    }
    __syncthreads();
    const int w = tid >> 6, l = tid & 63;
    float4 s = f4add(f4add(part[w][l], part[w][l+64]),
                     f4add(part[w][l+128], part[w][l+192]));
    #pragma unroll
    for (int off = 32; off > 0; off >>= 1) {
      s.x += __shfl_xor(s.x, off);
      s.y += __shfl_xor(s.y, off);
      s.z += __shfl_xor(s.z, off);
      s.w += __shfl_xor(s.w, off);
    }
    if (l == 0) dots[base + tk0 + w] = s;
    __syncthreads();
  }
}

// Phase 2: merge structure for batch b (one 256-thread block).
__device__ inline void phase2_merge(int b, int tid,
                                    const float4* __restrict__ dots,
                                    const int* __restrict__ attn,
                                    const int* __restrict__ spec,
                                    const float* __restrict__ gum,
                                    const float* __restrict__ bias,
                                    float* __restrict__ out,
                                    float* __restrict__ v_ws,
                                    int* __restrict__ seg_ws,
                                    int* __restrict__ meta,
                                    int* sums, unsigned char* wantL, int* seg,
                                    int* sTp) {
  const float b0 = bias[0], b1 = bias[1];

  // ---- T = sum(attention_mask[b]) ----
  int tsum = 0;
  #pragma unroll
  for (int k = 0; k < 8; ++k) tsum += attn[b*Sq + tid*8 + k];
  sums[tid] = tsum; __syncthreads();
  for (int off = 128; off > 0; off >>= 1) {
    if (tid < off) sums[tid] += sums[tid+off];
    __syncthreads();
  }
  if (tid == 0) *sTp = sums[0];
  __syncthreads();
  const int T = *sTp;

  // ---- per-position logits / mm / want / v ----
  int wloc[8];
  #pragma unroll
  for (int k = 0; k < 8; ++k) {
    const int i  = tid*8 + k;
    const int gi = b*Sq + i;
    float4 di = dots[gi];
    float l0, l1;
    if (i < Sq-1) {
      float4 dn = dots[gi+1];
      l0 = (di.x + dn.z) + b0;
      l1 = (di.y + dn.w) + b1;
    } else { l0 = b0; l1 = b1; }
    out[OFF_LG + (size_t)gi*2 + 0] = l0;
    out[OFF_LG + (size_t)gi*2 + 1] = l1;
    float z0 = l0 + gum[(size_t)gi*2 + 0];
    float z1 = l1 + gum[(size_t)gi*2 + 1];
    float m  = fmaxf(z0, z1);
    float e0 = expf(z0 - m), e1 = expf(z1 - m);
    float den = e0 + e1;
    float p0 = e0 / den, p1 = e1 / den;
    int idx1 = (p1 > p0) ? 1 : 0;             // np.argmax: first max wins
    float h0f = idx1 ? 0.0f : 1.0f, h1f = idx1 ? 1.0f : 0.0f;
    float mm0 = (h0f - p0) + p0;              // straight-through numerics
    float mm1 = (h1f - p1) + p1;
    if (spec[gi] != 0) { mm0 = 1.0f; mm1 = 0.0f; }
    float am = (float)attn[gi];
    mm0 *= am; mm1 *= am;
    out[OFF_MM + (size_t)gi*2 + 0] = mm0;
    out[OFF_MM + (size_t)gi*2 + 1] = mm1;
    int want = (mm1 > 0.5f) && (i >= 1) && (i < T-1);
    wantL[i] = (unsigned char)want;
    wloc[k]  = want;
    float v = want ? mm1 : mm0;
    if (i == 0) v = 1.0f;
    if (i >= T) v = 0.0f;
    v_ws[gi] = v;
  }
  __syncthreads();

  // ---- inc + thread-local inclusive scan ----
  int incs[8]; int run = 0;
  #pragma unroll
  for (int k = 0; k < 8; ++k) {
    const int i = tid*8 + k;
    int wprev = (i >= 1) ? (int)wantL[i-1] : 0;
    int inc = (i < T && i >= 1 && !(wloc[k] && wprev)) ? 1 : 0;
    run += inc;
    incs[k] = run;
  }
  sums[tid] = run; __syncthreads();
  // Hillis-Steele inclusive scan over 256 thread totals
  for (int off = 1; off < 256; off <<= 1) {
    int val = (tid >= off) ? sums[tid - off] : 0;
    __syncthreads();
    sums[tid] += val;
    __syncthreads();
  }
  const int excl = sums[tid] - run;
  const int total = sums[255];

  // ---- segment starts ----
  if (tid == 0) seg[0] = 0;
  #pragma unroll
  for (int k = 0; k < 8; ++k) {
    const int i = tid*8 + k;
    int inc = (k == 0) ? incs[0] : (incs[k] - incs[k-1]);
    if (inc) seg[excl + incs[k]] = i;
  }
  __syncthreads();

  const int nl = total + 1;
  if (tid == 0) { meta[b*2] = nl; meta[b*2+1] = T; }

  // ---- counts / masks / seg to global ----
  #pragma unroll
  for (int k = 0; k < 8; ++k) {
    const int t  = tid*8 + k;
    const int gi = b*Sq + t;
    seg_ws[gi] = (t < nl) ? seg[t] : 0;
    float cnt = 0.0f, mam = 0.0f, msp = 0.0f;
    if (t < nl) {
      int s0 = seg[t];
      int s1 = (t+1 < nl) ? seg[t+1] : T;
      cnt = (float)(s1 - s0);
      mam = 1.0f;
    }
    if (t == 0 || t == nl-1) msp = 1.0f;
    out[OFF_MAM + gi] = mam;
    out[OFF_MSP + gi] = msp;
    out[OFF_CNT + gi] = cnt;
  }
}

// Phase 3: chunked segment gather for block `blk` (16 output rows).
__device__ inline void phase3_gather(int blk, int tid,
                                     const float* __restrict__ hid,
                                     const float* __restrict__ v_ws,
                                     const int* __restrict__ seg_ws,
                                     const int* __restrict__ meta,
                                     float* __restrict__ out_mh,
                                     int* bound) {
  const int blocksPerBatch = Sq / K3_ROWS;            // 128
  const int b  = blk / blocksPerBatch;
  const int t0 = (blk % blocksPerBatch) * K3_ROWS;
  const int nl = meta[b*2];
  const int T  = meta[b*2+1];

  if (tid <= K3_ROWS) {
    const int t = t0 + tid;
    bound[tid] = (t < nl) ? seg_ws[b*Sq + t] : T;
  }
  __syncthreads();

  const int rbase = b*Sq;
  int i = bound[0];
  #pragma unroll 1
  for (int r = 0; r < K3_ROWS; ++r) {
    float4 a0 = make_float4(0.f,0.f,0.f,0.f), a1 = a0;
    const int s1 = bound[r+1];
    for (; i < s1; ++i) {
      const float w = v_ws[rbase + i];
      const float4* hr = (const float4*)(hid + (size_t)(rbase + i) * Hq);
      const float4 x0 = hr[tid];
      const float4 x1 = hr[256 + tid];
      a0.x = fmaf(w, x0.x, a0.x); a0.y = fmaf(w, x0.y, a0.y);
      a0.z = fmaf(w, x0.z, a0.z); a0.w = fmaf(w, x0.w, a0.w);
      a1.x = fmaf(w, x1.x, a1.x); a1.y = fmaf(w, x1.y, a1.y);
      a1.z = fmaf(w, x1.z, a1.z); a1.w = fmaf(w, x1.w, a1.w);
    }
    float4* orow = (float4*)(out_mh + (size_t)(rbase + t0 + r) * Hq);
    nt_store_f4(a0, orow + tid);
    nt_store_f4(a1, orow + 256 + tid);
  }
}

// ======================= fused cooperative kernel ===========================
// 1024 blocks x 256 threads; 4 blocks/CU co-resident (LDS 27.4KB, VGPR<=128).
__global__ __launch_bounds__(256, 4) void fused_all(
    const float* __restrict__ hid, const int* __restrict__ attn,
    const int* __restrict__ spec, const float* __restrict__ gum,
    const float* __restrict__ Wg, const float* __restrict__ bias,
    float* __restrict__ out, float4* __restrict__ dots,
    float* __restrict__ v_ws, int* __restrict__ seg_ws,
    int* __restrict__ meta) {
  __shared__ float4 part[4][256];          // 16 KB (phase 1)
  __shared__ int sums[256];                // 1 KB  (phase 2)
  __shared__ unsigned char wantL[Sq];      // 2 KB  (phase 2)
  __shared__ int seg[Sq];                  // 8 KB  (phase 2)
  __shared__ int sT;                       //       (phase 2)
  __shared__ int bound[K3_ROWS + 1];       //       (phase 3)

  cg::grid_group grid = cg::this_grid();
  const int blk = blockIdx.x, tid = threadIdx.x;

  phase1_dots(blk, tid, hid, Wg, dots, part);

  __threadfence();          // dots visible device-wide (cross-XCD)
  grid.sync();

  if (blk < Bq)
    phase2_merge(blk, tid, dots, attn, spec, gum, bias, out,
                 v_ws, seg_ws, meta, sums, wantL, seg, &sT);

  __threadfence();          // v_ws/seg_ws/meta visible device-wide
  grid.sync();

  phase3_gather(blk, tid, hid, v_ws, seg_ws, meta, out + OFF_MH, bound);
}

// ======================= fallback 3-kernel path =============================
__global__ __launch_bounds__(256) void k1_dots(const float* __restrict__ hid,
                                               const float* __restrict__ Wg,
                                               float4* __restrict__ dots) {
  __shared__ float4 part[4][256];
  phase1_dots(blockIdx.x, threadIdx.x, hid, Wg, dots, part);
}

__global__ __launch_bounds__(256) void k2_merge(const float4* __restrict__ dots,
                                                const int* __restrict__ attn,
                                                const int* __restrict__ spec,
                                                const float* __restrict__ gum,
                                                const float* __restrict__ bias,
                                                float* __restrict__ out,
                                                float* __restrict__ v_ws,
                                                int* __restrict__ seg_ws,
                                                int* __restrict__ meta) {
  __shared__ int sums[256];
  __shared__ unsigned char wantL[Sq];
  __shared__ int seg[Sq];
  __shared__ int sT;
  phase2_merge(blockIdx.x, threadIdx.x, dots, attn, spec, gum, bias, out,
               v_ws, seg_ws, meta, sums, wantL, seg, &sT);
}

__global__ __launch_bounds__(256) void k3_gather(const float* __restrict__ hid,
                                                 const float* __restrict__ v_ws,
                                                 const int* __restrict__ seg_ws,
                                                 const int* __restrict__ meta,
                                                 float* __restrict__ out_mh) {
  __shared__ int bound[K3_ROWS + 1];
  phase3_gather(blockIdx.x, threadIdx.x, hid, v_ws, seg_ws, meta, out_mh, bound);
}

extern "C" void kernel_launch(void* const* d_in, const int* in_sizes, int n_in,
                              void* d_out, int out_size, void* d_ws, size_t ws_size,
                              hipStream_t stream) {
  (void)in_sizes; (void)n_in; (void)out_size; (void)ws_size;
  const float* hid  = (const float*)d_in[0];
  const int*   attn = (const int*)d_in[1];
  const int*   spec = (const int*)d_in[2];
  const float* gum  = (const float*)d_in[3];
  const float* Wg   = (const float*)d_in[4];
  const float* bias = (const float*)d_in[5];
  float* out = (float*)d_out;
  char*  ws  = (char*)d_ws;
  float4* dots  = (float4*)(ws + WS_DOTS);
  float* v_ws   = (float*)(ws + WS_V);
  int*   seg_ws = (int*)(ws + WS_SEG);
  int*   meta   = (int*)(ws + WS_META);

  void* kargs[] = { (void*)&hid, (void*)&attn, (void*)&spec, (void*)&gum,
                    (void*)&Wg, (void*)&bias, (void*)&out, (void*)&dots,
                    (void*)&v_ws, (void*)&seg_ws, (void*)&meta };
  hipError_t err = hipLaunchCooperativeKernel((const void*)fused_all,
                                              dim3(GRIDN), dim3(256),
                                              kargs, 0, stream);
  if (err != hipSuccess) {
    // fallback: proven 3-kernel path
    k1_dots<<<dim3(GRIDN), dim3(256), 0, stream>>>(hid, Wg, dots);
    k2_merge<<<dim3(Bq), dim3(256), 0, stream>>>(dots, attn, spec, gum, bias,
                                                 out, v_ws, seg_ws, meta);
    k3_gather<<<dim3(Bq*(Sq/K3_ROWS)), dim3(256), 0, stream>>>(hid, v_ws, seg_ws,
                                                               meta, out + OFF_MH);
  }
}

// Round 4
// 446.104 us; speedup vs baseline: 1.3710x; 1.3710x over previous
//
#include <hip/hip_runtime.h>
#include <math.h>

#define Bq 8
#define Sq 2048
#define Hq 2048
#define BSq (Bq*Sq)
#define GRIDN (BSq/16)          // 1024 blocks, used for all three phases
#define K3_ROWS 16              // output rows per block in phase 3

// ---- output layout (flat float32, reference return order) ----
#define OFF_MH  ((size_t)0)                      // merged_hidden  [B,S,H]
#define OFF_MAM ((size_t)BSq*Hq)                 // merged_attention_mask [B,S]
#define OFF_MSP (OFF_MAM + (size_t)BSq)          // merged_special [B,S]
#define OFF_CNT (OFF_MSP + (size_t)BSq)          // counts [B,S]
#define OFF_MM  (OFF_CNT + (size_t)BSq)          // mm [B,S,2]
#define OFF_LG  (OFF_MM + (size_t)2*BSq)         // logits [B,S,2]

// ---- workspace layout (bytes) ----
#define WS_DOTS 0                                // float4[BSq] : d0,d1,e0,e1 per token
#define WS_V    ((size_t)BSq*16)                 // float[BSq]  : v weights
#define WS_SEG  (WS_V + (size_t)BSq*4)           // int[BSq]    : segment starts
#define WS_META (WS_SEG + (size_t)BSq*4)         // int[2*Bq]   : new_len, T per batch
#define WS_BAR  (WS_META + 64)                   // int[4]      : grid barrier counters

// clang-native 4-float vector (accepted by __builtin_nontemporal_store)
typedef float nfloat4 __attribute__((ext_vector_type(4)));

__device__ inline float4 f4add(float4 a, float4 b) {
  return make_float4(a.x+b.x, a.y+b.y, a.z+b.z, a.w+b.w);
}

__device__ inline void nt_store_f4(float4 v, float4* p) {
  nfloat4 nv;
  nv.x = v.x; nv.y = v.y; nv.z = v.z; nv.w = v.w;
  __builtin_nontemporal_store(nv, (nfloat4*)p);
}

// ---- agent-scope (cross-XCD coherent, L2-bypassing) helpers ----
__device__ inline float ld_af(const float* p) {
  return __hip_atomic_load(p, __ATOMIC_RELAXED, __HIP_MEMORY_SCOPE_AGENT);
}
__device__ inline int ld_ai(const int* p) {
  return __hip_atomic_load(p, __ATOMIC_RELAXED, __HIP_MEMORY_SCOPE_AGENT);
}
__device__ inline void st_af(float* p, float v) {
  __hip_atomic_store(p, v, __ATOMIC_RELAXED, __HIP_MEMORY_SCOPE_AGENT);
}
__device__ inline void st_ai(int* p, int v) {
  __hip_atomic_store(p, v, __ATOMIC_RELAXED, __HIP_MEMORY_SCOPE_AGENT);
}
__device__ inline float4 ld_af4(const float* p) {
  float4 r;
  r.x = ld_af(p+0); r.y = ld_af(p+1); r.z = ld_af(p+2); r.w = ld_af(p+3);
  return r;
}

// Manual grid barrier: release-add + relaxed agent spin (NO buffer_inv, so
// clean hid lines stay valid in each XCD L2 across the barrier).
__device__ inline void grid_barrier(int* cnt, int expected) {
  __syncthreads();
  if (threadIdx.x == 0) {
    __hip_atomic_fetch_add(cnt, 1, __ATOMIC_RELEASE, __HIP_MEMORY_SCOPE_AGENT);
    while (__hip_atomic_load(cnt, __ATOMIC_RELAXED, __HIP_MEMORY_SCOPE_AGENT)
           < expected)
      __builtin_amdgcn_s_sleep(2);
  }
  __syncthreads();
}

// ======================= phase bodies (shared by fused + fallback) ==========

// Phase 1: per-token dots. 16 tokens per block `blk`, 256 threads.
__device__ inline void phase1_dots(int blk, int tid,
                                   const float* __restrict__ hid,
                                   const float* __restrict__ Wg,
                                   float* __restrict__ dots,  // float4-laid-out
                                   float4 (*part)[256]) {
  const float4* W4 = (const float4*)Wg;
  const float4 wa0 = W4[2*tid],           wa1 = W4[2*tid+1];
  const float4 wa2 = W4[2*(256+tid)],     wa3 = W4[2*(256+tid)+1];
  const float4 wb0 = W4[1024+2*tid],      wb1 = W4[1024+2*tid+1];
  const float4 wb2 = W4[1024+2*(256+tid)],wb3 = W4[1024+2*(256+tid)+1];
  const int base = blk * 16;
  for (int tk0 = 0; tk0 < 16; tk0 += 4) {
    #pragma unroll
    for (int j = 0; j < 4; ++j) {
      const float4* hr = (const float4*)(hid + (size_t)(base + tk0 + j) * Hq);
      float4 h0 = hr[tid], h1 = hr[256+tid];
      float d0 = h0.x*wa0.x + h0.y*wa0.z + h0.z*wa1.x + h0.w*wa1.z
               + h1.x*wa2.x + h1.y*wa2.z + h1.z*wa3.x + h1.w*wa3.z;
      float d1 = h0.x*wa0.y + h0.y*wa0.w + h0.z*wa1.y + h0.w*wa1.w
               + h1.x*wa2.y + h1.y*wa2.w + h1.z*wa3.y + h1.w*wa3.w;
      float e0 = h0.x*wb0.x + h0.y*wb0.z + h0.z*wb1.x + h0.w*wb1.z
               + h1.x*wb2.x + h1.y*wb2.z + h1.z*wb3.x + h1.w*wb3.z;
      float e1 = h0.x*wb0.y + h0.y*wb0.w + h0.z*wb1.y + h0.w*wb1.w
               + h1.x*wb2.y + h1.y*wb2.w + h1.z*wb3.y + h1.w*wb3.w;
      part[j][tid] = make_float4(d0, d1, e0, e1);
    }
    __syncthreads();
    const int w = tid >> 6, l = tid & 63;
    float4 s = f4add(f4add(part[w][l], part[w][l+64]),
                     f4add(part[w][l+128], part[w][l+192]));
    #pragma unroll
    for (int off = 32; off > 0; off >>= 1) {
      s.x += __shfl_xor(s.x, off);
      s.y += __shfl_xor(s.y, off);
      s.z += __shfl_xor(s.z, off);
      s.w += __shfl_xor(s.w, off);
    }
    if (l == 0) {
      float* dp = dots + (size_t)(base + tk0 + w) * 4;
      st_af(dp+0, s.x); st_af(dp+1, s.y); st_af(dp+2, s.z); st_af(dp+3, s.w);
    }
    __syncthreads();
  }
}

// Phase 2: merge structure for batch b (one 256-thread block).
__device__ inline void phase2_merge(int b, int tid,
                                    const float* __restrict__ dots,
                                    const int* __restrict__ attn,
                                    const int* __restrict__ spec,
                                    const float* __restrict__ gum,
                                    const float* __restrict__ bias,
                                    float* __restrict__ out,
                                    float* __restrict__ v_ws,
                                    int* __restrict__ seg_ws,
                                    int* __restrict__ meta,
                                    int* sums, unsigned char* wantL, int* seg,
                                    int* sTp) {
  const float b0 = bias[0], b1 = bias[1];

  // ---- T = sum(attention_mask[b]) ----
  int tsum = 0;
  #pragma unroll
  for (int k = 0; k < 8; ++k) tsum += attn[b*Sq + tid*8 + k];
  sums[tid] = tsum; __syncthreads();
  for (int off = 128; off > 0; off >>= 1) {
    if (tid < off) sums[tid] += sums[tid+off];
    __syncthreads();
  }
  if (tid == 0) *sTp = sums[0];
  __syncthreads();
  const int T = *sTp;

  // ---- per-position logits / mm / want / v ----
  int wloc[8];
  #pragma unroll
  for (int k = 0; k < 8; ++k) {
    const int i  = tid*8 + k;
    const int gi = b*Sq + i;
    float4 di = ld_af4(dots + (size_t)gi*4);
    float l0, l1;
    if (i < Sq-1) {
      float4 dn = ld_af4(dots + (size_t)(gi+1)*4);
      l0 = (di.x + dn.z) + b0;
      l1 = (di.y + dn.w) + b1;
    } else { l0 = b0; l1 = b1; }
    out[OFF_LG + (size_t)gi*2 + 0] = l0;
    out[OFF_LG + (size_t)gi*2 + 1] = l1;
    float z0 = l0 + gum[(size_t)gi*2 + 0];
    float z1 = l1 + gum[(size_t)gi*2 + 1];
    float m  = fmaxf(z0, z1);
    float e0 = expf(z0 - m), e1 = expf(z1 - m);
    float den = e0 + e1;
    float p0 = e0 / den, p1 = e1 / den;
    int idx1 = (p1 > p0) ? 1 : 0;             // np.argmax: first max wins
    float h0f = idx1 ? 0.0f : 1.0f, h1f = idx1 ? 1.0f : 0.0f;
    float mm0 = (h0f - p0) + p0;              // straight-through numerics
    float mm1 = (h1f - p1) + p1;
    if (spec[gi] != 0) { mm0 = 1.0f; mm1 = 0.0f; }
    float am = (float)attn[gi];
    mm0 *= am; mm1 *= am;
    out[OFF_MM + (size_t)gi*2 + 0] = mm0;
    out[OFF_MM + (size_t)gi*2 + 1] = mm1;
    int want = (mm1 > 0.5f) && (i >= 1) && (i < T-1);
    wantL[i] = (unsigned char)want;
    wloc[k]  = want;
    float v = want ? mm1 : mm0;
    if (i == 0) v = 1.0f;
    if (i >= T) v = 0.0f;
    st_af(&v_ws[gi], v);
  }
  __syncthreads();

  // ---- inc + thread-local inclusive scan ----
  int incs[8]; int run = 0;
  #pragma unroll
  for (int k = 0; k < 8; ++k) {
    const int i = tid*8 + k;
    int wprev = (i >= 1) ? (int)wantL[i-1] : 0;
    int inc = (i < T && i >= 1 && !(wloc[k] && wprev)) ? 1 : 0;
    run += inc;
    incs[k] = run;
  }
  sums[tid] = run; __syncthreads();
  // Hillis-Steele inclusive scan over 256 thread totals
  for (int off = 1; off < 256; off <<= 1) {
    int val = (tid >= off) ? sums[tid - off] : 0;
    __syncthreads();
    sums[tid] += val;
    __syncthreads();
  }
  const int excl = sums[tid] - run;
  const int total = sums[255];

  // ---- segment starts ----
  if (tid == 0) seg[0] = 0;
  #pragma unroll
  for (int k = 0; k < 8; ++k) {
    const int i = tid*8 + k;
    int inc = (k == 0) ? incs[0] : (incs[k] - incs[k-1]);
    if (inc) seg[excl + incs[k]] = i;
  }
  __syncthreads();

  const int nl = total + 1;
  if (tid == 0) { st_ai(&meta[b*2], nl); st_ai(&meta[b*2+1], T); }

  // ---- counts / masks / seg to global ----
  #pragma unroll
  for (int k = 0; k < 8; ++k) {
    const int t  = tid*8 + k;
    const int gi = b*Sq + t;
    st_ai(&seg_ws[gi], (t < nl) ? seg[t] : 0);
    float cnt = 0.0f, mam = 0.0f, msp = 0.0f;
    if (t < nl) {
      int s0 = seg[t];
      int s1 = (t+1 < nl) ? seg[t+1] : T;
      cnt = (float)(s1 - s0);
      mam = 1.0f;
    }
    if (t == 0 || t == nl-1) msp = 1.0f;
    out[OFF_MAM + gi] = mam;
    out[OFF_MSP + gi] = msp;
    out[OFF_CNT + gi] = cnt;
  }
}

// Phase 3: chunked, software-pipelined segment gather (16 output rows/block).
__device__ inline void phase3_gather(int blk, int tid,
                                     const float* __restrict__ hid,
                                     const float* __restrict__ v_ws,
                                     const int* __restrict__ seg_ws,
                                     const int* __restrict__ meta,
                                     float* __restrict__ out_mh,
                                     int* bound, float* vsh) {
  const int blocksPerBatch = Sq / K3_ROWS;            // 128
  const int b  = blk / blocksPerBatch;
  const int t0 = (blk % blocksPerBatch) * K3_ROWS;
  const int nl = ld_ai(&meta[b*2]);
  const int T  = ld_ai(&meta[b*2+1]);

  if (tid <= K3_ROWS) {
    const int t = t0 + tid;
    bound[tid] = (t < nl) ? ld_ai(&seg_ws[b*Sq + t]) : T;
  }
  __syncthreads();

  const int rbase = b*Sq;
  const int i0 = bound[0], iN = bound[K3_ROWS];
  // cache this block's v-weights in LDS (range <= Sq floats)
  for (int i = i0 + tid; i < iN; i += 256)
    vsh[i - i0] = ld_af(&v_ws[rbase + i]);
  __syncthreads();

  const size_t orow0 = (size_t)(rbase + t0) * Hq;
  int i = i0, r = 0;
  float4 a0 = make_float4(0.f,0.f,0.f,0.f), a1 = a0;
  float4 nx0 = a0, nx1 = a0;
  if (i < iN) {
    const float4* hr = (const float4*)(hid + (size_t)(rbase + i) * Hq);
    nx0 = hr[tid]; nx1 = hr[256 + tid];
  }
  while (r < K3_ROWS) {
    // emit rows whose segment ends at current i (empty segments -> zeros)
    while (r < K3_ROWS && i >= bound[r+1]) {
      float4* orow = (float4*)(out_mh + orow0 + (size_t)r * Hq);
      nt_store_f4(a0, orow + tid);
      nt_store_f4(a1, orow + 256 + tid);
      a0 = make_float4(0.f,0.f,0.f,0.f); a1 = a0;
      ++r;
    }
    if (r >= K3_ROWS) break;
    const float4 x0 = nx0, x1 = nx1;
    const float w = vsh[i - i0];
    if (i + 1 < iN) {   // prefetch next row while accumulating this one
      const float4* hr = (const float4*)(hid + (size_t)(rbase + i + 1) * Hq);
      nx0 = hr[tid]; nx1 = hr[256 + tid];
    }
    a0.x = fmaf(w, x0.x, a0.x); a0.y = fmaf(w, x0.y, a0.y);
    a0.z = fmaf(w, x0.z, a0.z); a0.w = fmaf(w, x0.w, a0.w);
    a1.x = fmaf(w, x1.x, a1.x); a1.y = fmaf(w, x1.y, a1.y);
    a1.z = fmaf(w, x1.z, a1.z); a1.w = fmaf(w, x1.w, a1.w);
    ++i;
  }
}

// ======================= fused kernel (manual grid barrier) =================
__global__ __launch_bounds__(256, 4) void fused_all(
    const float* __restrict__ hid, const int* __restrict__ attn,
    const int* __restrict__ spec, const float* __restrict__ gum,
    const float* __restrict__ Wg, const float* __restrict__ bias,
    float* __restrict__ out, float* __restrict__ dots,
    float* __restrict__ v_ws, int* __restrict__ seg_ws,
    int* __restrict__ meta, int* __restrict__ bar) {
  __shared__ float4 part[4][256];          // 16 KB (phase 1)
  __shared__ int sums[256];                // 1 KB  (phase 2)
  __shared__ unsigned char wantL[Sq];      // 2 KB  (phase 2)
  __shared__ int seg[Sq];                  // 8 KB  (phase 2)
  __shared__ int sT;                       //       (phase 2)
  __shared__ int bound[K3_ROWS + 1];       //       (phase 3)
  __shared__ float vsh[Sq];                // 8 KB  (phase 3)

  const int blk = blockIdx.x, tid = threadIdx.x;

  phase1_dots(blk, tid, hid, Wg, dots, part);

  grid_barrier(&bar[0], GRIDN);

  if (blk < Bq)
    phase2_merge(blk, tid, dots, attn, spec, gum, bias, out,
                 v_ws, seg_ws, meta, sums, wantL, seg, &sT);

  grid_barrier(&bar[1], GRIDN);

  phase3_gather(blk, tid, hid, v_ws, seg_ws, meta, out + OFF_MH, bound, vsh);
}

// ======================= fallback 3-kernel path =============================
__global__ __launch_bounds__(256) void k1_dots(const float* __restrict__ hid,
                                               const float* __restrict__ Wg,
                                               float* __restrict__ dots) {
  __shared__ float4 part[4][256];
  phase1_dots(blockIdx.x, threadIdx.x, hid, Wg, dots, part);
}

__global__ __launch_bounds__(256) void k2_merge(const float* __restrict__ dots,
                                                const int* __restrict__ attn,
                                                const int* __restrict__ spec,
                                                const float* __restrict__ gum,
                                                const float* __restrict__ bias,
                                                float* __restrict__ out,
                                                float* __restrict__ v_ws,
                                                int* __restrict__ seg_ws,
                                                int* __restrict__ meta) {
  __shared__ int sums[256];
  __shared__ unsigned char wantL[Sq];
  __shared__ int seg[Sq];
  __shared__ int sT;
  phase2_merge(blockIdx.x, threadIdx.x, dots, attn, spec, gum, bias, out,
               v_ws, seg_ws, meta, sums, wantL, seg, &sT);
}

__global__ __launch_bounds__(256) void k3_gather(const float* __restrict__ hid,
                                                 const float* __restrict__ v_ws,
                                                 const int* __restrict__ seg_ws,
                                                 const int* __restrict__ meta,
                                                 float* __restrict__ out_mh) {
  __shared__ int bound[K3_ROWS + 1];
  __shared__ float vsh[Sq];
  phase3_gather(blockIdx.x, threadIdx.x, hid, v_ws, seg_ws, meta, out_mh,
                bound, vsh);
}

extern "C" void kernel_launch(void* const* d_in, const int* in_sizes, int n_in,
                              void* d_out, int out_size, void* d_ws, size_t ws_size,
                              hipStream_t stream) {
  (void)in_sizes; (void)n_in; (void)out_size;
  const float* hid  = (const float*)d_in[0];
  const int*   attn = (const int*)d_in[1];
  const int*   spec = (const int*)d_in[2];
  const float* gum  = (const float*)d_in[3];
  const float* Wg   = (const float*)d_in[4];
  const float* bias = (const float*)d_in[5];
  float* out = (float*)d_out;
  char*  ws  = (char*)d_ws;
  float* dots   = (float*)(ws + WS_DOTS);
  float* v_ws   = (float*)(ws + WS_V);
  int*   seg_ws = (int*)(ws + WS_SEG);
  int*   meta   = (int*)(ws + WS_META);
  int*   bar    = (int*)(ws + WS_BAR);

  hipError_t err = hipErrorUnknown;
  if (ws_size >= WS_BAR + 16) {
    hipMemsetAsync(ws + WS_BAR, 0, 16, stream);   // zero barrier counters
    void* kargs[] = { (void*)&hid, (void*)&attn, (void*)&spec, (void*)&gum,
                      (void*)&Wg, (void*)&bias, (void*)&out, (void*)&dots,
                      (void*)&v_ws, (void*)&seg_ws, (void*)&meta, (void*)&bar };
    err = hipLaunchCooperativeKernel((const void*)fused_all,
                                     dim3(GRIDN), dim3(256),
                                     kargs, 0, stream);
  }
  if (err != hipSuccess) {
    // fallback: proven 3-kernel path
    k1_dots<<<dim3(GRIDN), dim3(256), 0, stream>>>(hid, Wg, dots);
    k2_merge<<<dim3(Bq), dim3(256), 0, stream>>>(dots, attn, spec, gum, bias,
                                                 out, v_ws, seg_ws, meta);
    k3_gather<<<dim3(Bq*(Sq/K3_ROWS)), dim3(256), 0, stream>>>(hid, v_ws, seg_ws,
                                                               meta, out + OFF_MH);
  }
}

// Round 5
// 271.979 us; speedup vs baseline: 2.2488x; 1.6402x over previous
//
#include <hip/hip_runtime.h>
#include <math.h>

#define Bq 8
#define Sq 2048
#define Hq 2048
#define BSq (Bq*Sq)
#define K3_ROWS 8               // output rows per k3 block -> 2048 blocks

// ---- output layout (flat float32, reference return order) ----
#define OFF_MH  ((size_t)0)                      // merged_hidden  [B,S,H]
#define OFF_MAM ((size_t)BSq*Hq)                 // merged_attention_mask [B,S]
#define OFF_MSP (OFF_MAM + (size_t)BSq)          // merged_special [B,S]
#define OFF_CNT (OFF_MSP + (size_t)BSq)          // counts [B,S]
#define OFF_MM  (OFF_CNT + (size_t)BSq)          // mm [B,S,2]
#define OFF_LG  (OFF_MM + (size_t)2*BSq)         // logits [B,S,2]

// ---- workspace layout (bytes) ----
#define WS_DOTS 0                                // float4[BSq] : d0,d1,e0,e1 per token
#define WS_V    ((size_t)BSq*16)                 // float[BSq]  : v weights
#define WS_SEG  (WS_V + (size_t)BSq*4)           // int[BSq]    : segment starts
#define WS_META (WS_SEG + (size_t)BSq*4)         // int[2*Bq]   : new_len, T per batch

// clang-native 4-float vector (accepted by __builtin_nontemporal_store)
typedef float nfloat4 __attribute__((ext_vector_type(4)));

__device__ inline float4 f4add(float4 a, float4 b) {
  return make_float4(a.x+b.x, a.y+b.y, a.z+b.z, a.w+b.w);
}

__device__ inline void nt_store_f4(float4 v, float4* p) {
  nfloat4 nv;
  nv.x = v.x; nv.y = v.y; nv.z = v.z; nv.w = v.w;
  __builtin_nontemporal_store(nv, (nfloat4*)p);
}

// ---------------- Kernel 1: per-token dots (round-2 proven) ----------------
__global__ __launch_bounds__(256) void k1_dots(const float* __restrict__ hid,
                                               const float* __restrict__ Wg,
                                               float4* __restrict__ dots) {
  __shared__ float4 part[4][256];
  const int tid = threadIdx.x;
  const float4* W4 = (const float4*)Wg;
  // W row-major (4096,2): w_j(h) = W[2h+j]; e-half at float offset 4096 (float4 idx 1024)
  const float4 wa0 = W4[2*tid],           wa1 = W4[2*tid+1];
  const float4 wa2 = W4[2*(256+tid)],     wa3 = W4[2*(256+tid)+1];
  const float4 wb0 = W4[1024+2*tid],      wb1 = W4[1024+2*tid+1];
  const float4 wb2 = W4[1024+2*(256+tid)],wb3 = W4[1024+2*(256+tid)+1];
  const int base = blockIdx.x * 16;
  for (int tk0 = 0; tk0 < 16; tk0 += 4) {
    #pragma unroll
    for (int j = 0; j < 4; ++j) {
      const float4* hr = (const float4*)(hid + (size_t)(base + tk0 + j) * Hq);
      float4 h0 = hr[tid], h1 = hr[256+tid];
      float d0 = h0.x*wa0.x + h0.y*wa0.z + h0.z*wa1.x + h0.w*wa1.z
               + h1.x*wa2.x + h1.y*wa2.z + h1.z*wa3.x + h1.w*wa3.z;
      float d1 = h0.x*wa0.y + h0.y*wa0.w + h0.z*wa1.y + h0.w*wa1.w
               + h1.x*wa2.y + h1.y*wa2.w + h1.z*wa3.y + h1.w*wa3.w;
      float e0 = h0.x*wb0.x + h0.y*wb0.z + h0.z*wb1.x + h0.w*wb1.z
               + h1.x*wb2.x + h1.y*wb2.z + h1.z*wb3.x + h1.w*wb3.z;
      float e1 = h0.x*wb0.y + h0.y*wb0.w + h0.z*wb1.y + h0.w*wb1.w
               + h1.x*wb2.y + h1.y*wb2.w + h1.z*wb3.y + h1.w*wb3.w;
      part[j][tid] = make_float4(d0, d1, e0, e1);
    }
    __syncthreads();
    const int w = tid >> 6, l = tid & 63;
    float4 s = f4add(f4add(part[w][l], part[w][l+64]),
                     f4add(part[w][l+128], part[w][l+192]));
    #pragma unroll
    for (int off = 32; off > 0; off >>= 1) {
      s.x += __shfl_xor(s.x, off);
      s.y += __shfl_xor(s.y, off);
      s.z += __shfl_xor(s.z, off);
      s.w += __shfl_xor(s.w, off);
    }
    if (l == 0) dots[base + tk0 + w] = s;
    __syncthreads();
  }
}

// ---------------- Kernel 2: merge structure (round-2 proven) ----------------
__global__ __launch_bounds__(256) void k2_merge(const float4* __restrict__ dots,
                                                const int* __restrict__ attn,
                                                const int* __restrict__ spec,
                                                const float* __restrict__ gum,
                                                const float* __restrict__ bias,
                                                float* __restrict__ out,
                                                float* __restrict__ v_ws,
                                                int* __restrict__ seg_ws,
                                                int* __restrict__ meta) {
  const int b = blockIdx.x, tid = threadIdx.x;
  __shared__ int sums[256];
  __shared__ unsigned char wantL[Sq];
  __shared__ int seg[Sq];
  __shared__ int sT;
  const float b0 = bias[0], b1 = bias[1];

  // ---- T = sum(attention_mask[b]) ----
  int tsum = 0;
  #pragma unroll
  for (int k = 0; k < 8; ++k) tsum += attn[b*Sq + tid*8 + k];
  sums[tid] = tsum; __syncthreads();
  for (int off = 128; off > 0; off >>= 1) {
    if (tid < off) sums[tid] += sums[tid+off];
    __syncthreads();
  }
  if (tid == 0) sT = sums[0];
  __syncthreads();
  const int T = sT;

  // ---- per-position logits / mm / want / v ----
  int wloc[8];
  #pragma unroll
  for (int k = 0; k < 8; ++k) {
    const int i  = tid*8 + k;
    const int gi = b*Sq + i;
    float4 di = dots[gi];
    float l0, l1;
    if (i < Sq-1) {
      float4 dn = dots[gi+1];
      l0 = (di.x + dn.z) + b0;
      l1 = (di.y + dn.w) + b1;
    } else { l0 = b0; l1 = b1; }
    out[OFF_LG + (size_t)gi*2 + 0] = l0;
    out[OFF_LG + (size_t)gi*2 + 1] = l1;
    float z0 = l0 + gum[(size_t)gi*2 + 0];
    float z1 = l1 + gum[(size_t)gi*2 + 1];
    float m  = fmaxf(z0, z1);
    float e0 = expf(z0 - m), e1 = expf(z1 - m);
    float den = e0 + e1;
    float p0 = e0 / den, p1 = e1 / den;
    int idx1 = (p1 > p0) ? 1 : 0;             // np.argmax: first max wins
    float h0f = idx1 ? 0.0f : 1.0f, h1f = idx1 ? 1.0f : 0.0f;
    float mm0 = (h0f - p0) + p0;              // straight-through numerics
    float mm1 = (h1f - p1) + p1;
    if (spec[gi] != 0) { mm0 = 1.0f; mm1 = 0.0f; }
    float am = (float)attn[gi];
    mm0 *= am; mm1 *= am;
    out[OFF_MM + (size_t)gi*2 + 0] = mm0;
    out[OFF_MM + (size_t)gi*2 + 1] = mm1;
    int want = (mm1 > 0.5f) && (i >= 1) && (i < T-1);
    wantL[i] = (unsigned char)want;
    wloc[k]  = want;
    float v = want ? mm1 : mm0;
    if (i == 0) v = 1.0f;
    if (i >= T) v = 0.0f;
    v_ws[gi] = v;
  }
  __syncthreads();

  // ---- inc + thread-local inclusive scan ----
  int incs[8]; int run = 0;
  #pragma unroll
  for (int k = 0; k < 8; ++k) {
    const int i = tid*8 + k;
    int wprev = (i >= 1) ? (int)wantL[i-1] : 0;
    int inc = (i < T && i >= 1 && !(wloc[k] && wprev)) ? 1 : 0;
    run += inc;
    incs[k] = run;
  }
  sums[tid] = run; __syncthreads();
  // Hillis-Steele inclusive scan over 256 thread totals
  for (int off = 1; off < 256; off <<= 1) {
    int val = (tid >= off) ? sums[tid - off] : 0;
    __syncthreads();
    sums[tid] += val;
    __syncthreads();
  }
  const int excl = sums[tid] - run;
  const int total = sums[255];

  // ---- segment starts ----
  if (tid == 0) seg[0] = 0;
  #pragma unroll
  for (int k = 0; k < 8; ++k) {
    const int i = tid*8 + k;
    int inc = (k == 0) ? incs[0] : (incs[k] - incs[k-1]);
    if (inc) seg[excl + incs[k]] = i;
  }
  __syncthreads();

  const int nl = total + 1;
  if (tid == 0) { meta[b*2] = nl; meta[b*2+1] = T; }

  // ---- counts / masks / seg to global ----
  #pragma unroll
  for (int k = 0; k < 8; ++k) {
    const int t  = tid*8 + k;
    const int gi = b*Sq + t;
    seg_ws[gi] = (t < nl) ? seg[t] : 0;
    float cnt = 0.0f, mam = 0.0f, msp = 0.0f;
    if (t < nl) {
      int s0 = seg[t];
      int s1 = (t+1 < nl) ? seg[t+1] : T;
      cnt = (float)(s1 - s0);
      mam = 1.0f;
    }
    if (t == 0 || t == nl-1) msp = 1.0f;
    out[OFF_MAM + gi] = mam;
    out[OFF_MSP + gi] = msp;
    out[OFF_CNT + gi] = cnt;
  }
}

// ---------------- Kernel 3: pipelined segment gather ------------------------
// 8 output rows/block (2048 blocks -> 8 blocks/CU of TLP). The block streams
// input rows [bound[0], bound[8]) once, forward; 2-deep register pipeline
// (c = row i, n = row i+1, f = row i+2 issued before row i's FMAs) with only
// statically-named registers (no runtime-indexed arrays -> no scratch).
__global__ __launch_bounds__(256) void k3_gather(const float* __restrict__ hid,
                                                 const float* __restrict__ v_ws,
                                                 const int* __restrict__ seg_ws,
                                                 const int* __restrict__ meta,
                                                 float* __restrict__ out_mh) {
  const int blocksPerBatch = Sq / K3_ROWS;            // 256
  const int b  = blockIdx.x / blocksPerBatch;
  const int t0 = (blockIdx.x % blocksPerBatch) * K3_ROWS;
  const int tid = threadIdx.x;
  const int nl = meta[b*2];
  const int T  = meta[b*2+1];

  __shared__ int bound[K3_ROWS + 1];
  if (tid <= K3_ROWS) {
    const int t = t0 + tid;
    bound[tid] = (t < nl) ? seg_ws[b*Sq + t] : T;
  }
  __syncthreads();

  const int rbase = b*Sq;
  const int i0 = bound[0], iN = bound[K3_ROWS];

  const float4 z4 = make_float4(0.f,0.f,0.f,0.f);
  float4 c0 = z4, c1 = z4, n0 = z4, n1 = z4;
  float wc = 0.f, wn = 0.f;
  if (i0 < iN) {
    const float4* hr = (const float4*)(hid + (size_t)(rbase + i0) * Hq);
    c0 = hr[tid]; c1 = hr[256 + tid]; wc = v_ws[rbase + i0];
  }
  if (i0 + 1 < iN) {
    const float4* hr = (const float4*)(hid + (size_t)(rbase + i0 + 1) * Hq);
    n0 = hr[tid]; n1 = hr[256 + tid]; wn = v_ws[rbase + i0 + 1];
  }

  int i = i0, r = 0;
  float4 a0 = z4, a1 = z4;
  while (r < K3_ROWS) {
    // emit rows whose segment ends at current i (empty segments -> zeros)
    while (r < K3_ROWS && i >= bound[r + 1]) {
      float4* orow = (float4*)(out_mh + (size_t)(rbase + t0 + r) * Hq);
      nt_store_f4(a0, orow + tid);
      nt_store_f4(a1, orow + 256 + tid);
      a0 = z4; a1 = z4;
      ++r;
    }
    if (r >= K3_ROWS) break;
    // issue row i+2 loads before consuming row i
    float4 f0 = z4, f1 = z4; float wf = 0.f;
    if (i + 2 < iN) {
      const float4* hr = (const float4*)(hid + (size_t)(rbase + i + 2) * Hq);
      f0 = hr[tid]; f1 = hr[256 + tid]; wf = v_ws[rbase + i + 2];
    }
    a0.x = fmaf(wc, c0.x, a0.x); a0.y = fmaf(wc, c0.y, a0.y);
    a0.z = fmaf(wc, c0.z, a0.z); a0.w = fmaf(wc, c0.w, a0.w);
    a1.x = fmaf(wc, c1.x, a1.x); a1.y = fmaf(wc, c1.y, a1.y);
    a1.z = fmaf(wc, c1.z, a1.z); a1.w = fmaf(wc, c1.w, a1.w);
    c0 = n0; c1 = n1; wc = wn;
    n0 = f0; n1 = f1; wn = wf;
    ++i;
  }
}

extern "C" void kernel_launch(void* const* d_in, const int* in_sizes, int n_in,
                              void* d_out, int out_size, void* d_ws, size_t ws_size,
                              hipStream_t stream) {
  (void)in_sizes; (void)n_in; (void)out_size; (void)ws_size;
  const float* hid  = (const float*)d_in[0];
  const int*   attn = (const int*)d_in[1];
  const int*   spec = (const int*)d_in[2];
  const float* gum  = (const float*)d_in[3];
  const float* Wg   = (const float*)d_in[4];
  const float* bias = (const float*)d_in[5];
  float* out = (float*)d_out;
  char*  ws  = (char*)d_ws;
  float4* dots  = (float4*)(ws + WS_DOTS);
  float* v_ws   = (float*)(ws + WS_V);
  int*   seg_ws = (int*)(ws + WS_SEG);
  int*   meta   = (int*)(ws + WS_META);

  k1_dots<<<dim3(BSq/16), dim3(256), 0, stream>>>(hid, Wg, dots);
  k2_merge<<<dim3(Bq), dim3(256), 0, stream>>>(dots, attn, spec, gum, bias,
                                               out, v_ws, seg_ws, meta);
  k3_gather<<<dim3(Bq*(Sq/K3_ROWS)), dim3(256), 0, stream>>>(hid, v_ws, seg_ws,
                                                             meta, out + OFF_MH);
}